// Round 9
// baseline (589.338 us; speedup 1.0000x reference)
//
#include <hip/hip_runtime.h>
#include <cmath>

#define NGRID 128
#define FEAT 16
#define WIDTH 64
#define NPTS 262144
#define IN_MLP 25
#define NBUCKETS 4096    // 16^3 coarse buckets (8^3 cells each)

// ws layout: [0, 16384): bucket counters/offsets (4096 int)
//            [16384, 16384+NPTS*4): permutation (point ids in bucket order)
//            [16384+NPTS*4, 16384+NPTS*8): cached bucket keys
#define WS_PERM_OFF (NBUCKETS * 4)
#define WS_KEY_OFF  (NBUCKETS * 4 + NPTS * 4)
#define WS_NEEDED   (NBUCKETS * 4 + NPTS * 8)

__device__ __forceinline__ int bucket_of(const float* __restrict__ x, int p) {
    int key = 0;
    #pragma unroll
    for (int d = 0; d < 3; ++d) {
        int i0 = (int)floorf(x[3 * p + d] * 127.0f);
        i0 = i0 < 0 ? 0 : (i0 > 126 ? 126 : i0);
        key = (key << 4) | (i0 >> 3);
    }
    return key;
}

__global__ void zero_hist_kernel(int* __restrict__ hist) {
    hist[blockIdx.x * 256 + threadIdx.x] = 0;
}

__global__ void hist_kernel(const float* __restrict__ x, int* __restrict__ hist,
                            int* __restrict__ keys) {
    const int p = blockIdx.x * blockDim.x + threadIdx.x;
    if (p >= NPTS) return;
    const int k = bucket_of(x, p);
    keys[p] = k;
    atomicAdd(&hist[k], 1);
}

// Exclusive scan of 4096 ints, single block of 1024 threads.
__global__ __launch_bounds__(1024) void scan_kernel(int* __restrict__ hist) {
    __shared__ int lds[1024];
    const int t = threadIdx.x;
    int4 v = ((int4*)hist)[t];
    lds[t] = v.x + v.y + v.z + v.w;
    __syncthreads();
    #pragma unroll
    for (int off = 1; off < 1024; off <<= 1) {
        int val = lds[t];
        int add = (t >= off) ? lds[t - off] : 0;
        __syncthreads();
        lds[t] = val + add;
        __syncthreads();
    }
    const int excl = (t == 0) ? 0 : lds[t - 1];
    int4 o;
    o.x = excl;
    o.y = excl + v.x;
    o.z = excl + v.x + v.y;
    o.w = excl + v.x + v.y + v.z;
    ((int4*)hist)[t] = o;
}

__global__ void scatter_kernel(const int* __restrict__ keys, int* __restrict__ offs,
                               int* __restrict__ perm) {
    const int p = blockIdx.x * blockDim.x + threadIdx.x;
    if (p >= NPTS) return;
    const int pos = atomicAdd(&offs[keys[p]], 1);
    perm[pos] = p;
}

__device__ __forceinline__ void fma4(float4& a, float w, const float4 c) {
    a.x = fmaf(w, c.x, a.x);
    a.y = fmaf(w, c.y, a.y);
    a.z = fmaf(w, c.z, a.z);
    a.w = fmaf(w, c.w, a.w);
}

// launch_bounds (128,4): 4 waves/EU -> VGPR cap 128. Grid supplies only
// 16 waves/CU (262144 threads / 256 CU), so 4 waves/EU is the actual max;
// an (128,8) bound would cap VGPR at 64 and re-introduce spills under the
// unroll-2 gather below.
template <bool SORTED>
__global__ __launch_bounds__(128, 4) void gridnet_kernel(
    const float* __restrict__ x,
    const float* __restrict__ grid,
    const float* __restrict__ w1,
    const float* __restrict__ b1,
    const float* __restrict__ w2,
    const float* __restrict__ b2,
    const int* __restrict__ perm,
    float* __restrict__ out)
{
    // XCD-chunked swizzle: 2048 blocks, 8 XCDs -> XCD k gets a contiguous
    // sorted-point range (contiguous spatial slab) for private-L2 locality.
    const int bid = blockIdx.x;
    const int swz = SORTED ? ((bid & 7) * 256 + (bid >> 3)) : bid;
    const int gid = swz * 128 + threadIdx.x;
    const int p = SORTED ? perm[gid] : gid;

    // ---- per-dimension index + cubic weight setup ----
    int   offa[4], offb[4], offc[4];
    float wx[4], wy[4], wz[4];
    float t[3];
    #pragma unroll
    for (int d = 0; d < 3; ++d) {
        const float u  = x[3 * p + d] * 127.0f;   // x * (n - 1)
        const float fu = floorf(u);
        const float td = u - fu;
        t[d] = td;
        const int i0 = (int)fu;
        const float t2 = td * td;
        const float t3 = t2 * td;
        float w0 = 0.5f * (-t3 + 2.0f * t2 - td);
        float w1v = 0.5f * (3.0f * t3 - 5.0f * t2 + 2.0f);
        float w2v = 0.5f * (-3.0f * t3 + 4.0f * t2 + td);
        float w3 = 0.5f * (t3 - t2);
        #pragma unroll
        for (int o = 0; o < 4; ++o) {
            int v = i0 - 1 + o;
            v = v < 0 ? 0 : (v > 127 ? 127 : v);
            if (d == 0) offa[o] = v * 65536;   // *128*128*4 (float4 units)
            if (d == 1) offb[o] = v * 512;     // *128*4
            if (d == 2) offc[o] = v * 4;       // *4
        }
        float* wp = (d == 0) ? wx : (d == 1) ? wy : wz;
        wp[0] = w0; wp[1] = w1v; wp[2] = w2v; wp[3] = w3;
    }

    // ---- tricubic gather: 64 cells x 16 feats ----
    // unroll 2 on the y-row loop: two z-rows (8 cells = 32 float4) in flight
    // -> 2x outstanding misses per thread. Latency-bound per R8 counters
    // (2.76 TB/s fetch, 6.8% VALU, 45% occ).
    float4 acc0 = make_float4(0.f, 0.f, 0.f, 0.f);
    float4 acc1 = acc0, acc2 = acc0, acc3 = acc0;
    const float4* __restrict__ g4 = (const float4*)grid;

    #pragma unroll 1
    for (int a = 0; a < 4; ++a) {
        const float wa = wx[a];
        #pragma unroll 2
        for (int b = 0; b < 4; ++b) {
            const float wab = wa * wy[b];
            const int   rb  = offa[a] + offb[b];
            #pragma unroll
            for (int c = 0; c < 4; ++c) {
                const float w = wab * wz[c];
                const float4* cell = g4 + (rb + offc[c]);
                fma4(acc0, w, cell[0]);
                fma4(acc1, w, cell[1]);
                fma4(acc2, w, cell[2]);
                fma4(acc3, w, cell[3]);
            }
        }
    }

    // ---- assemble MLP input: 16 feats + 9 positional sins ----
    float h[IN_MLP];
    h[0]  = acc0.x; h[1]  = acc0.y; h[2]  = acc0.z; h[3]  = acc0.w;
    h[4]  = acc1.x; h[5]  = acc1.y; h[6]  = acc1.z; h[7]  = acc1.w;
    h[8]  = acc2.x; h[9]  = acc2.y; h[10] = acc2.z; h[11] = acc2.w;
    h[12] = acc3.x; h[13] = acc3.y; h[14] = acc3.z; h[15] = acc3.w;

    // sin(2*pi*k*t) == v_sin_f32(k*t): gfx950 v_sin takes REVOLUTIONS.
    #pragma unroll
    for (int k = 0; k < 3; ++k) {
        #pragma unroll
        for (int d = 0; d < 3; ++d) {
            h[16 + k * 3 + d] = __builtin_amdgcn_sinf((float)(k + 1) * t[d]);
        }
    }

    // ---- MLP: 25 -> 64 (swish) -> 1 (wave-uniform weight reads -> s_load) ----
    float o = b2[0];
    #pragma unroll 4
    for (int j = 0; j < WIDTH; ++j) {
        float hj = b1[j];
        #pragma unroll
        for (int k = 0; k < IN_MLP; ++k) {
            hj = fmaf(h[k], w1[j * IN_MLP + k], hj);
        }
        const float sig = 1.0f / (1.0f + __expf(-hj));
        o = fmaf(hj * sig, w2[j], o);
    }
    out[p] = o;
}

extern "C" void kernel_launch(void* const* d_in, const int* in_sizes, int n_in,
                              void* d_out, int out_size, void* d_ws, size_t ws_size,
                              hipStream_t stream) {
    const float* x    = (const float*)d_in[0];
    const float* grid = (const float*)d_in[1];
    const float* w1   = (const float*)d_in[2];
    const float* b1   = (const float*)d_in[3];
    const float* w2   = (const float*)d_in[4];
    const float* b2   = (const float*)d_in[5];
    float* out = (float*)d_out;

    if (ws_size >= (size_t)WS_NEEDED) {
        int* hist = (int*)d_ws;
        int* perm = (int*)((char*)d_ws + WS_PERM_OFF);
        int* keys = (int*)((char*)d_ws + WS_KEY_OFF);
        zero_hist_kernel<<<NBUCKETS / 256, 256, 0, stream>>>(hist);
        hist_kernel<<<NPTS / 256, 256, 0, stream>>>(x, hist, keys);
        scan_kernel<<<1, 1024, 0, stream>>>(hist);
        scatter_kernel<<<NPTS / 256, 256, 0, stream>>>(keys, hist, perm);
        gridnet_kernel<true><<<NPTS / 128, 128, 0, stream>>>(
            x, grid, w1, b1, w2, b2, perm, out);
    } else {
        gridnet_kernel<false><<<NPTS / 128, 128, 0, stream>>>(
            x, grid, w1, b1, w2, b2, nullptr, out);
    }
}

// Round 10
// 574.090 us; speedup vs baseline: 1.0266x; 1.0266x over previous
//
#include <hip/hip_runtime.h>
#include <cmath>

#define NGRID 128
#define FEAT 16
#define WIDTH 64
#define NPTS 262144
#define IN_MLP 25
#define NBUCKETS 4096    // 16^3 coarse buckets (8^3 cells each)

// ws layout: [0,16K): bucket counters/offsets
//            [16K, 16K+NPTS*4): cached bucket keys
//            [16K+NPTS*4, ...): sorted float4 {x,y,z, bits(point_id)}
#define WS_KEY_OFF (NBUCKETS * 4)
#define WS_XS_OFF  (NBUCKETS * 4 + NPTS * 4)
#define WS_NEEDED  (NBUCKETS * 4 + NPTS * 4 + NPTS * 16)

__device__ __forceinline__ int bucket_of3(float x0, float x1, float x2) {
    int key = 0;
    const float c[3] = {x0, x1, x2};
    #pragma unroll
    for (int d = 0; d < 3; ++d) {
        int i0 = (int)floorf(c[d] * 127.0f);
        i0 = i0 < 0 ? 0 : (i0 > 126 ? 126 : i0);
        key = (key << 4) | (i0 >> 3);
    }
    return key;
}

__global__ void hist_kernel(const float* __restrict__ x, int* __restrict__ hist,
                            int* __restrict__ keys) {
    const int p = blockIdx.x * blockDim.x + threadIdx.x;
    if (p >= NPTS) return;
    const int k = bucket_of3(x[3 * p], x[3 * p + 1], x[3 * p + 2]);
    keys[p] = k;
    atomicAdd(&hist[k], 1);
}

// Exclusive scan of 4096 ints, single block of 1024 threads.
__global__ __launch_bounds__(1024) void scan_kernel(int* __restrict__ hist) {
    __shared__ int lds[1024];
    const int t = threadIdx.x;
    int4 v = ((int4*)hist)[t];
    lds[t] = v.x + v.y + v.z + v.w;
    __syncthreads();
    #pragma unroll
    for (int off = 1; off < 1024; off <<= 1) {
        int val = lds[t];
        int add = (t >= off) ? lds[t - off] : 0;
        __syncthreads();
        lds[t] = val + add;
        __syncthreads();
    }
    const int excl = (t == 0) ? 0 : lds[t - 1];
    int4 o;
    o.x = excl;
    o.y = excl + v.x;
    o.z = excl + v.x + v.y;
    o.w = excl + v.x + v.y + v.z;
    ((int4*)hist)[t] = o;
}

// Writes sorted {x,y,z,point_id} so the gather kernel needs ONE coalesced
// float4 load instead of perm[gid] -> x[3p] (two serial scattered loads).
__global__ void scatter_kernel(const float* __restrict__ x,
                               const int* __restrict__ keys,
                               int* __restrict__ offs,
                               float4* __restrict__ xs) {
    const int p = blockIdx.x * blockDim.x + threadIdx.x;
    if (p >= NPTS) return;
    const int pos = atomicAdd(&offs[keys[p]], 1);
    xs[pos] = make_float4(x[3 * p], x[3 * p + 1], x[3 * p + 2],
                          __int_as_float(p));
}

__device__ __forceinline__ void fma4(float4& a, float w, const float4 c) {
    a.x = fmaf(w, c.x, a.x);
    a.y = fmaf(w, c.y, a.y);
    a.z = fmaf(w, c.z, a.z);
    a.w = fmaf(w, c.w, a.w);
}

// 2 lanes per point: 524288 threads = 32 waves/CU demand -> ~full occupancy
// (R9 showed the grid, at 16 waves/CU, was the latency-hiding cap).
// Each lane gathers 2 of the 4 x-slices; pair-reduce via shfl_xor(1).
template <bool SORTED>
__global__ __launch_bounds__(256, 8) void gridnet_kernel(
    const float* __restrict__ x,
    const float* __restrict__ grid,
    const float* __restrict__ w1,
    const float* __restrict__ b1,
    const float* __restrict__ w2,
    const float* __restrict__ b2,
    const float4* __restrict__ xs,
    float* __restrict__ out)
{
    // XCD-chunked swizzle: 2048 blocks, 8 XCDs -> contiguous spatial slab
    // per XCD's private L2.
    const int bid = blockIdx.x;
    const int swz = SORTED ? ((bid & 7) * 256 + (bid >> 3)) : bid;
    const int g   = swz * 256 + threadIdx.x;
    const int s    = g >> 1;   // point slot
    const int half = g & 1;    // which pair of x-slices this lane gathers

    float xc[3];
    int p;
    if (SORTED) {
        const float4 v = xs[s];
        xc[0] = v.x; xc[1] = v.y; xc[2] = v.z;
        p = __float_as_int(v.w);
    } else {
        p = s;
        xc[0] = x[3 * p]; xc[1] = x[3 * p + 1]; xc[2] = x[3 * p + 2];
    }

    // ---- per-dimension index + cubic weight setup ----
    int   offa[4], offb[4], offc[4];
    float wx[4], wy[4], wz[4];
    float t[3];
    #pragma unroll
    for (int d = 0; d < 3; ++d) {
        const float u  = xc[d] * 127.0f;   // x * (n - 1)
        const float fu = floorf(u);
        const float td = u - fu;
        t[d] = td;
        const int i0 = (int)fu;
        const float t2 = td * td;
        const float t3 = t2 * td;
        float w0 = 0.5f * (-t3 + 2.0f * t2 - td);
        float w1v = 0.5f * (3.0f * t3 - 5.0f * t2 + 2.0f);
        float w2v = 0.5f * (-3.0f * t3 + 4.0f * t2 + td);
        float w3 = 0.5f * (t3 - t2);
        #pragma unroll
        for (int o = 0; o < 4; ++o) {
            int v = i0 - 1 + o;
            v = v < 0 ? 0 : (v > 127 ? 127 : v);
            if (d == 0) offa[o] = v * 65536;   // *128*128*4 (float4 units)
            if (d == 1) offb[o] = v * 512;     // *128*4
            if (d == 2) offc[o] = v * 4;       // *4
        }
        float* wp = (d == 0) ? wx : (d == 1) ? wy : wz;
        wp[0] = w0; wp[1] = w1v; wp[2] = w2v; wp[3] = w3;
    }

    // ---- half tricubic gather: 32 cells (2 x-slices) per lane ----
    float4 acc0 = make_float4(0.f, 0.f, 0.f, 0.f);
    float4 acc1 = acc0, acc2 = acc0, acc3 = acc0;
    const float4* __restrict__ g4 = (const float4*)grid;

    #pragma unroll 1
    for (int aj = 0; aj < 2; ++aj) {
        const int   a  = 2 * half + aj;
        const float wa = wx[a];
        const int   oa = offa[a];
        #pragma unroll 1
        for (int b = 0; b < 4; ++b) {
            const float wab = wa * wy[b];
            const int   rb  = oa + offb[b];
            #pragma unroll
            for (int c = 0; c < 4; ++c) {
                const float w = wab * wz[c];
                const float4* cell = g4 + (rb + offc[c]);
                fma4(acc0, w, cell[0]);
                fma4(acc1, w, cell[1]);
                fma4(acc2, w, cell[2]);
                fma4(acc3, w, cell[3]);
            }
        }
    }

    // ---- pair reduction: lane g += lane g^1 (same wave, adjacent lanes) ----
    float h[IN_MLP];
    h[0]=acc0.x; h[1]=acc0.y; h[2]=acc0.z;  h[3]=acc0.w;
    h[4]=acc1.x; h[5]=acc1.y; h[6]=acc1.z;  h[7]=acc1.w;
    h[8]=acc2.x; h[9]=acc2.y; h[10]=acc2.z; h[11]=acc2.w;
    h[12]=acc3.x;h[13]=acc3.y;h[14]=acc3.z; h[15]=acc3.w;
    #pragma unroll
    for (int i = 0; i < 16; ++i) h[i] += __shfl_xor(h[i], 1);

    // sin(2*pi*k*t) == v_sin_f32(k*t): gfx950 v_sin takes REVOLUTIONS.
    #pragma unroll
    for (int k = 0; k < 3; ++k) {
        #pragma unroll
        for (int d = 0; d < 3; ++d) {
            h[16 + k * 3 + d] = __builtin_amdgcn_sinf((float)(k + 1) * t[d]);
        }
    }

    // ---- MLP: 25 -> 64 (swish) -> 1, computed redundantly by both lanes
    // (VALU was 6% busy; redundancy is free vs a divergent branch) ----
    float o = b2[0];
    #pragma unroll 4
    for (int j = 0; j < WIDTH; ++j) {
        float hj = b1[j];
        #pragma unroll
        for (int k = 0; k < IN_MLP; ++k) {
            hj = fmaf(h[k], w1[j * IN_MLP + k], hj);
        }
        const float sig = 1.0f / (1.0f + __expf(-hj));
        o = fmaf(hj * sig, w2[j], o);
    }
    if (half == 0) out[p] = o;
}

extern "C" void kernel_launch(void* const* d_in, const int* in_sizes, int n_in,
                              void* d_out, int out_size, void* d_ws, size_t ws_size,
                              hipStream_t stream) {
    const float* x    = (const float*)d_in[0];
    const float* grid = (const float*)d_in[1];
    const float* w1   = (const float*)d_in[2];
    const float* b1   = (const float*)d_in[3];
    const float* w2   = (const float*)d_in[4];
    const float* b2   = (const float*)d_in[5];
    float* out = (float*)d_out;

    const int nthreads = 2 * NPTS;          // 2 lanes per point
    const int nblocks  = nthreads / 256;    // 2048

    if (ws_size >= (size_t)WS_NEEDED) {
        int*    hist = (int*)d_ws;
        int*    keys = (int*)((char*)d_ws + WS_KEY_OFF);
        float4* xs   = (float4*)((char*)d_ws + WS_XS_OFF);
        hipMemsetAsync(hist, 0, NBUCKETS * 4, stream);
        hist_kernel<<<NPTS / 512, 512, 0, stream>>>(x, hist, keys);
        scan_kernel<<<1, 1024, 0, stream>>>(hist);
        scatter_kernel<<<NPTS / 512, 512, 0, stream>>>(x, keys, hist, xs);
        gridnet_kernel<true><<<nblocks, 256, 0, stream>>>(
            x, grid, w1, b1, w2, b2, xs, out);
    } else {
        gridnet_kernel<false><<<nblocks, 256, 0, stream>>>(
            x, grid, w1, b1, w2, b2, nullptr, out);
    }
}